// Round 1
// baseline (290.615 us; speedup 1.0000x reference)
//
#include <hip/hip_runtime.h>

// MultiGridAgentEncoder: x = [query(13) | grey slots 4x13 | yellow slots 4x13] (117, pad->128)
// out = relu(x @ W + b), W (117,256) f32, out (B,256) f32.
// Strategy: fused gather->LDS(bf16) + per-wave register-held W bf16 fragments + 16x16x32 bf16 MFMA.

#define TM 128          // rows per block
#define XS_LD 136       // LDS row stride in halves (128 + 8 pad: spreads quad-bank groups)
#define THREADS 512     // 8 waves: wave grid 2 (rows) x 4 (cols)
#define NCOL 256
#define KDIM 117

typedef short short8 __attribute__((ext_vector_type(8)));
typedef float f32x4 __attribute__((ext_vector_type(4)));

__device__ __forceinline__ short f2bf(float x) {
    // round-to-nearest-even f32 -> bf16 (bits in a short)
    unsigned u = __builtin_bit_cast(unsigned, x);
    unsigned r = (u + 0x7fffu + ((u >> 16) & 1u)) >> 16;
    return (short)r;
}

__device__ __forceinline__ void write_agent(short* xrow, int dst,
                                            const float* pos, const float* dir,
                                            const float* abil, const float* carr,
                                            const float* stat, size_t a) {
    const float2 p  = ((const float2*)pos)[a];
    const float4 d  = ((const float4*)dir)[a];
    const float2 ab = ((const float2*)abil)[a];
    const float2 ca = ((const float2*)carr)[a];
    const float* st = stat + a * 3;
    xrow[dst + 0]  = f2bf(p.x);
    xrow[dst + 1]  = f2bf(p.y);
    xrow[dst + 2]  = f2bf(d.x);
    xrow[dst + 3]  = f2bf(d.y);
    xrow[dst + 4]  = f2bf(d.z);
    xrow[dst + 5]  = f2bf(d.w);
    xrow[dst + 6]  = f2bf(ab.x);
    xrow[dst + 7]  = f2bf(ab.y);
    xrow[dst + 8]  = f2bf(ca.x);
    xrow[dst + 9]  = f2bf(ca.y);
    xrow[dst + 10] = f2bf(st[0]);
    xrow[dst + 11] = f2bf(st[1]);
    xrow[dst + 12] = f2bf(st[2]);
}

__global__ __launch_bounds__(THREADS, 2)
void mga_encoder_kernel(const float* __restrict__ qpos, const float* __restrict__ qdir,
                        const float* __restrict__ qabil, const float* __restrict__ qcarr,
                        const float* __restrict__ qstat,
                        const float* __restrict__ apos, const float* __restrict__ adir,
                        const float* __restrict__ aabil, const float* __restrict__ acarr,
                        const float* __restrict__ astat,
                        const int* __restrict__ cidx,
                        const float* __restrict__ W, const float* __restrict__ bvec,
                        float* __restrict__ out) {
    __shared__ __align__(16) short Xs[TM * XS_LD];

    const int tid  = threadIdx.x;
    const int wave = tid >> 6;
    const int lane = tid & 63;
    const int ln   = lane & 15;   // col/row-in-tile lane index
    const int q    = lane >> 4;   // quad index (k-chunk / row-group)
    const int row0 = blockIdx.x * TM;

    // wave tile placement: rows (wave&1)*64, cols (wave>>1)*64
    const int r0w = (wave & 1) * 64;
    const int c0  = (wave >> 1) * 64;

    // ---- 1) per-wave W fragments (bf16) + bias into registers (long-latency,
    //         overlapped with LDS zero + gather below) ----
    short8 bfr[4][4];  // [kt][ct]: B[k = kt*32 + q*8 + j][n = c0 + ct*16 + ln]
    #pragma unroll
    for (int kt = 0; kt < 4; kt++) {
        #pragma unroll
        for (int ct = 0; ct < 4; ct++) {
            short8 f;
            #pragma unroll
            for (int j = 0; j < 8; j++) {
                int k = kt * 32 + q * 8 + j;
                float wv = (k < KDIM) ? W[(size_t)k * NCOL + c0 + ct * 16 + ln] : 0.f;
                f[j] = f2bf(wv);
            }
            bfr[kt][ct] = f;
        }
    }
    float bv[4];
    #pragma unroll
    for (int ct = 0; ct < 4; ct++) bv[ct] = bvec[c0 + ct * 16 + ln];

    // ---- 2) zero Xs (covers unfilled slots + K pad 117..127) ----
    {
        unsigned* z = (unsigned*)Xs;  // TM*XS_LD/2 = 8704 dwords = 512*17
        #pragma unroll
        for (int i = 0; i < 17; i++) z[tid + THREADS * i] = 0u;
    }
    __syncthreads();

    // ---- 3) gather: 4 threads per row ----
    {
        const int sub = tid & 3;
        const int r   = tid >> 2;          // 0..127
        const size_t b = (size_t)(row0 + r);
        short* xrow = &Xs[r * XS_LD];
        if (sub == 0) {
            // query features -> x[0..12]
            const float2 qp = ((const float2*)qpos)[b];
            const float4 qd = ((const float4*)qdir)[b];
            const float2 qa = ((const float2*)qabil)[b];
            const float2 qc = ((const float2*)qcarr)[b];
            const float* qs = qstat + b * 3;
            xrow[0]  = f2bf(qp.x);  xrow[1]  = f2bf(qp.y);
            xrow[2]  = f2bf(qd.x);  xrow[3]  = f2bf(qd.y);
            xrow[4]  = f2bf(qd.z);  xrow[5]  = f2bf(qd.w);
            xrow[6]  = f2bf(qa.x);  xrow[7]  = f2bf(qa.y);
            xrow[8]  = f2bf(qc.x);  xrow[9]  = f2bf(qc.y);
            xrow[10] = f2bf(qs[0]); xrow[11] = f2bf(qs[1]); xrow[12] = f2bf(qs[2]);
        } else if (sub == 1 || sub == 2) {
            // sub==1: grey (color idx 5) -> x[13..64]; sub==2: yellow (4) -> x[65..116]
            const int want = (sub == 1) ? 5 : 4;
            const int base = (sub == 1) ? 13 : 65;
            const int4* ip = (const int4*)(cidx + b * 16);
            int4 a0 = ip[0], a1 = ip[1], a2 = ip[2], a3 = ip[3];
            int c[16] = {a0.x, a0.y, a0.z, a0.w, a1.x, a1.y, a1.z, a1.w,
                         a2.x, a2.y, a2.z, a2.w, a3.x, a3.y, a3.z, a3.w};
            int cnt = 0;
            #pragma unroll
            for (int j = 0; j < 16; j++) {
                if (c[j] == want && cnt < 4) {
                    write_agent(xrow, base + cnt * 13, apos, adir, aabil, acarr, astat,
                                b * 16 + (size_t)j);
                    cnt++;
                }
            }
        }
    }
    __syncthreads();

    // ---- 4) MFMA: wave computes 64 rows x 64 cols (4x4 tiles of 16x16) ----
    f32x4 acc[4][4];
    #pragma unroll
    for (int rt = 0; rt < 4; rt++)
        #pragma unroll
        for (int ct = 0; ct < 4; ct++) acc[rt][ct] = (f32x4){0.f, 0.f, 0.f, 0.f};

    #pragma unroll
    for (int kt = 0; kt < 4; kt++) {
        short8 av[4];
        #pragma unroll
        for (int rt = 0; rt < 4; rt++) {
            // A[m = r0w + rt*16 + ln][k = kt*32 + q*8 + j], contiguous 8 halves (16B aligned)
            av[rt] = *(const short8*)&Xs[(r0w + rt * 16 + ln) * XS_LD + kt * 32 + q * 8];
        }
        #pragma unroll
        for (int rt = 0; rt < 4; rt++)
            #pragma unroll
            for (int ct = 0; ct < 4; ct++)
                acc[rt][ct] = __builtin_amdgcn_mfma_f32_16x16x32_bf16(
                    av[rt], bfr[kt][ct], acc[rt][ct], 0, 0, 0);
    }

    // ---- 5) epilogue: bias + relu, store f32 ----
    #pragma unroll
    for (int rt = 0; rt < 4; rt++) {
        #pragma unroll
        for (int ct = 0; ct < 4; ct++) {
            #pragma unroll
            for (int i = 0; i < 4; i++) {
                int row = row0 + r0w + rt * 16 + q * 4 + i;
                int col = c0 + ct * 16 + ln;
                float v = acc[rt][ct][i] + bv[ct];
                out[(size_t)row * NCOL + col] = fmaxf(v, 0.f);
            }
        }
    }
}

extern "C" void kernel_launch(void* const* d_in, const int* in_sizes, int n_in,
                              void* d_out, int out_size, void* d_ws, size_t ws_size,
                              hipStream_t stream) {
    const float* qpos  = (const float*)d_in[0];
    const float* qdir  = (const float*)d_in[1];
    const float* qabil = (const float*)d_in[2];
    const float* qcarr = (const float*)d_in[3];
    const float* qstat = (const float*)d_in[4];
    const float* apos  = (const float*)d_in[5];
    const float* adir  = (const float*)d_in[6];
    const float* aabil = (const float*)d_in[7];
    const float* acarr = (const float*)d_in[8];
    const float* astat = (const float*)d_in[9];
    const int*   cidx  = (const int*)d_in[10];
    const float* W     = (const float*)d_in[11];
    const float* bvec  = (const float*)d_in[12];
    float* out = (float*)d_out;

    const int B = in_sizes[0] / 2;   // query_position is (B,2)
    const int nblocks = B / TM;      // 131072/128 = 1024

    mga_encoder_kernel<<<nblocks, THREADS, 0, stream>>>(
        qpos, qdir, qabil, qcarr, qstat, apos, adir, aabil, acarr, astat,
        cidx, W, bvec, out);
}

// Round 2
// 263.228 us; speedup vs baseline: 1.1040x; 1.1040x over previous
//
#include <hip/hip_runtime.h>

// MultiGridAgentEncoder: x = [query(13) | grey slots 4x13 | yellow slots 4x13] (117, pad->128)
// out = relu(x @ W + b), W (117,256) f32, out (B,256) f32.
// v2: ballot-based parallel gather (1 thread per row x agent), bf16 MFMA, reg-held W.

#define TM 128          // rows per block
#define XS_LD 136       // LDS row stride in halves (128 + 8 pad; keeps short8 16B-aligned)
#define THREADS 512     // 8 waves: wave grid 2 (rows) x 4 (cols)
#define NCOL 256
#define KDIM 117

typedef short short8 __attribute__((ext_vector_type(8)));
typedef float f32x4 __attribute__((ext_vector_type(4)));

__device__ __forceinline__ short f2bf(float x) {
    unsigned u = __builtin_bit_cast(unsigned, x);
    unsigned r = (u + 0x7fffu + ((u >> 16) & 1u)) >> 16;
    return (short)r;
}

__global__ __launch_bounds__(THREADS, 2)
void mga_encoder_kernel(const float* __restrict__ qpos, const float* __restrict__ qdir,
                        const float* __restrict__ qabil, const float* __restrict__ qcarr,
                        const float* __restrict__ qstat,
                        const float* __restrict__ apos, const float* __restrict__ adir,
                        const float* __restrict__ aabil, const float* __restrict__ acarr,
                        const float* __restrict__ astat,
                        const int* __restrict__ cidx,
                        const float* __restrict__ W, const float* __restrict__ bvec,
                        float* __restrict__ out) {
    __shared__ __align__(16) short Xs[TM * XS_LD];

    const int tid  = threadIdx.x;
    const int wave = tid >> 6;
    const int lane = tid & 63;
    const int ln   = lane & 15;   // col/row-in-tile lane index
    const int q    = lane >> 4;   // quad index (k-chunk / row-group)
    const int row0 = blockIdx.x * TM;

    const int r0w = (wave & 1) * 64;
    const int c0  = (wave >> 1) * 64;

    // ---- 1) per-wave W fragments (bf16) + bias into registers ----
    short8 bfr[4][4];  // [kt][ct]: B[k = kt*32 + q*8 + j][n = c0 + ct*16 + ln]
    #pragma unroll
    for (int kt = 0; kt < 4; kt++) {
        #pragma unroll
        for (int ct = 0; ct < 4; ct++) {
            short8 f;
            #pragma unroll
            for (int j = 0; j < 8; j++) {
                int k = kt * 32 + q * 8 + j;
                float wv = (k < KDIM) ? W[(size_t)k * NCOL + c0 + ct * 16 + ln] : 0.f;
                f[j] = f2bf(wv);
            }
            bfr[kt][ct] = f;
        }
    }
    float bv[4];
    #pragma unroll
    for (int ct = 0; ct < 4; ct++) bv[ct] = bvec[c0 + ct * 16 + ln];

    // ---- 2) zero Xs (unfilled slots + K pad) ----
    {
        unsigned* z = (unsigned*)Xs;  // TM*XS_LD/2 = 8704 dwords = 512*17
        #pragma unroll
        for (int i = 0; i < 17; i++) z[tid + THREADS * i] = 0u;
    }
    __syncthreads();

    // ---- 3) gather ----
    // 3a: agents — one thread per (row, agent). 16 threads/row, 32 rows/pass, 4 passes.
    {
        const int j  = tid & 15;          // agent index
        const int rr = tid >> 4;          // row-within-pass 0..31
        const int grp = lane & 0x30;      // start lane of my 16-lane row group
        const unsigned long long rowmask = 0xFFFFull << grp;
        const unsigned long long below   = (1ull << lane) - 1ull;

        int cs[4];
        #pragma unroll
        for (int p = 0; p < 4; p++)
            cs[p] = cidx[((size_t)(row0 + p * 32 + rr)) * 16 + j];

        #pragma unroll
        for (int p = 0; p < 4; p++) {
            const int r = p * 32 + rr;
            const size_t b = (size_t)(row0 + r);
            const int c = cs[p];
            const bool isg = (c == 5);    // grey
            const bool isy = (c == 4);    // yellow
            const unsigned long long bg = __ballot(isg);
            const unsigned long long by = __ballot(isy);
            if (isg | isy) {
                const unsigned long long bal = isg ? bg : by;
                const int rank = __popcll(bal & rowmask & below);
                if (rank < 4) {
                    const int dst = (isg ? 13 : 65) + rank * 13;
                    short* xrow = &Xs[r * XS_LD];
                    const size_t a = b * 16 + (size_t)j;
                    const float2 pp  = ((const float2*)apos)[a];
                    const float4 dd  = ((const float4*)adir)[a];
                    const float2 ab  = ((const float2*)aabil)[a];
                    const float2 ca  = ((const float2*)acarr)[a];
                    const float s0 = astat[a * 3 + 0];
                    const float s1 = astat[a * 3 + 1];
                    const float s2 = astat[a * 3 + 2];
                    xrow[dst + 0]  = f2bf(pp.x);
                    xrow[dst + 1]  = f2bf(pp.y);
                    xrow[dst + 2]  = f2bf(dd.x);
                    xrow[dst + 3]  = f2bf(dd.y);
                    xrow[dst + 4]  = f2bf(dd.z);
                    xrow[dst + 5]  = f2bf(dd.w);
                    xrow[dst + 6]  = f2bf(ab.x);
                    xrow[dst + 7]  = f2bf(ab.y);
                    xrow[dst + 8]  = f2bf(ca.x);
                    xrow[dst + 9]  = f2bf(ca.y);
                    xrow[dst + 10] = f2bf(s0);
                    xrow[dst + 11] = f2bf(s1);
                    xrow[dst + 12] = f2bf(s2);
                }
            }
        }
    }
    // 3b: query features — one thread per row (waves 0-1)
    if (tid < TM) {
        const size_t b = (size_t)(row0 + tid);
        short* xrow = &Xs[tid * XS_LD];
        const float2 qp = ((const float2*)qpos)[b];
        const float4 qd = ((const float4*)qdir)[b];
        const float2 qa = ((const float2*)qabil)[b];
        const float2 qc = ((const float2*)qcarr)[b];
        const float s0 = qstat[b * 3 + 0];
        const float s1 = qstat[b * 3 + 1];
        const float s2 = qstat[b * 3 + 2];
        xrow[0]  = f2bf(qp.x);  xrow[1]  = f2bf(qp.y);
        xrow[2]  = f2bf(qd.x);  xrow[3]  = f2bf(qd.y);
        xrow[4]  = f2bf(qd.z);  xrow[5]  = f2bf(qd.w);
        xrow[6]  = f2bf(qa.x);  xrow[7]  = f2bf(qa.y);
        xrow[8]  = f2bf(qc.x);  xrow[9]  = f2bf(qc.y);
        xrow[10] = f2bf(s0);    xrow[11] = f2bf(s1);    xrow[12] = f2bf(s2);
    }
    __syncthreads();

    // ---- 4) MFMA: wave computes 64 rows x 64 cols (4x4 tiles of 16x16) ----
    f32x4 acc[4][4];
    #pragma unroll
    for (int rt = 0; rt < 4; rt++)
        #pragma unroll
        for (int ct = 0; ct < 4; ct++) acc[rt][ct] = (f32x4){0.f, 0.f, 0.f, 0.f};

    #pragma unroll
    for (int kt = 0; kt < 4; kt++) {
        short8 av[4];
        #pragma unroll
        for (int rt = 0; rt < 4; rt++)
            av[rt] = *(const short8*)&Xs[(r0w + rt * 16 + ln) * XS_LD + kt * 32 + q * 8];
        #pragma unroll
        for (int rt = 0; rt < 4; rt++)
            #pragma unroll
            for (int ct = 0; ct < 4; ct++)
                acc[rt][ct] = __builtin_amdgcn_mfma_f32_16x16x32_bf16(
                    av[rt], bfr[kt][ct], acc[rt][ct], 0, 0, 0);
    }

    // ---- 5) epilogue: bias + relu, store f32 ----
    #pragma unroll
    for (int rt = 0; rt < 4; rt++) {
        #pragma unroll
        for (int ct = 0; ct < 4; ct++) {
            #pragma unroll
            for (int i = 0; i < 4; i++) {
                int row = row0 + r0w + rt * 16 + q * 4 + i;
                int col = c0 + ct * 16 + ln;
                float v = acc[rt][ct][i] + bv[ct];
                out[(size_t)row * NCOL + col] = fmaxf(v, 0.f);
            }
        }
    }
}

extern "C" void kernel_launch(void* const* d_in, const int* in_sizes, int n_in,
                              void* d_out, int out_size, void* d_ws, size_t ws_size,
                              hipStream_t stream) {
    const float* qpos  = (const float*)d_in[0];
    const float* qdir  = (const float*)d_in[1];
    const float* qabil = (const float*)d_in[2];
    const float* qcarr = (const float*)d_in[3];
    const float* qstat = (const float*)d_in[4];
    const float* apos  = (const float*)d_in[5];
    const float* adir  = (const float*)d_in[6];
    const float* aabil = (const float*)d_in[7];
    const float* acarr = (const float*)d_in[8];
    const float* astat = (const float*)d_in[9];
    const int*   cidx  = (const int*)d_in[10];
    const float* W     = (const float*)d_in[11];
    const float* bvec  = (const float*)d_in[12];
    float* out = (float*)d_out;

    const int B = in_sizes[0] / 2;   // query_position is (B,2)
    const int nblocks = B / TM;      // 131072/128 = 1024

    mga_encoder_kernel<<<nblocks, THREADS, 0, stream>>>(
        qpos, qdir, qabil, qcarr, qstat, apos, adir, aabil, acarr, astat,
        cidx, W, bvec, out);
}